// Round 1
// baseline (1098.487 us; speedup 1.0000x reference)
//
#include <hip/hip_runtime.h>

#define NEG_SLOPE 0.01f

// ---------------------------------------------------------------------------
// init: Xcur = X, res(d_out) = X, deg = 1.0 (self-loop)
// ---------------------------------------------------------------------------
__global__ void init_kernel(const float* __restrict__ X,
                            float* __restrict__ Xcur,
                            float* __restrict__ res,
                            float* __restrict__ deg,
                            int n, int nd) {
    int i = blockIdx.x * blockDim.x + threadIdx.x;
    if (i < nd) {
        float v = X[i];
        Xcur[i] = v;
        res[i]  = v;
    }
    if (i < n) deg[i] = 1.0f;
}

// deg[dst[e]] += 1 for each real edge
__global__ void degree_kernel(const int* __restrict__ dst,
                              float* __restrict__ deg, int e) {
    int i = blockIdx.x * blockDim.x + threadIdx.x;
    if (i < e) atomicAdd(&deg[dst[i]], 1.0f);
}

// in-place deg -> rsqrt(deg)   (deg >= 1 always, no zero case)
__global__ void rsqrt_kernel(float* __restrict__ deg, int n) {
    int i = blockIdx.x * blockDim.x + threadIdx.x;
    if (i < n) deg[i] = rsqrtf(deg[i]);
}

// ---------------------------------------------------------------------------
// xw = Xcur @ W   (W is 64x64 for this layer, staged in LDS)
// block = 256 threads = 4 rows x 64 cols
// ---------------------------------------------------------------------------
__global__ __launch_bounds__(256) void gemm_kernel(const float* __restrict__ Xc,
                                                   const float* __restrict__ W,
                                                   float* __restrict__ xw, int n) {
    __shared__ float Wl[64 * 64];
    __shared__ float Xl[4 * 64];
    int tid = threadIdx.x;
    #pragma unroll
    for (int j = 0; j < 16; ++j) Wl[j * 256 + tid] = W[j * 256 + tid];

    int lr  = tid >> 6;          // local row 0..3
    int c   = tid & 63;          // column 0..63
    int row = blockIdx.x * 4 + lr;
    if (row < n) Xl[lr * 64 + c] = Xc[row * 64 + c];
    __syncthreads();
    if (row < n) {
        float acc = 0.f;
        #pragma unroll
        for (int k = 0; k < 64; ++k)
            acc += Xl[lr * 64 + k] * Wl[k * 64 + c];
        xw[row * 64 + c] = acc;
    }
}

// ---------------------------------------------------------------------------
// agg[v][c] = b[c] + xw[v][c] * dinv[v]^2     (self-loop folded in)
// ---------------------------------------------------------------------------
__global__ void agg_init_kernel(const float* __restrict__ xw,
                                const float* __restrict__ dinv,
                                const float* __restrict__ b,
                                float* __restrict__ agg, int nd) {
    int i = blockIdx.x * blockDim.x + threadIdx.x;
    if (i < nd) {
        int v = i >> 6, c = i & 63;
        float dv = dinv[v];
        agg[i] = b[c] + xw[i] * dv * dv;
    }
}

// ---------------------------------------------------------------------------
// one wave (64 lanes) per edge: lane = channel
// agg[dst][c] += xw[src][c] * dinv[src]*dinv[dst]
// ---------------------------------------------------------------------------
__global__ __launch_bounds__(256) void scatter_kernel(const float* __restrict__ xw,
                                                      const int* __restrict__ src,
                                                      const int* __restrict__ dst,
                                                      const float* __restrict__ dinv,
                                                      float* __restrict__ agg, int e) {
    long long t = (long long)blockIdx.x * 256 + threadIdx.x;
    int eidx = (int)(t >> 6);
    int c    = (int)(t & 63);
    if (eidx < e) {
        int s = src[eidx];
        int d = dst[eidx];
        float norm = dinv[s] * dinv[d];
        atomicAdd(&agg[d * 64 + c], xw[s * 64 + c] * norm);
    }
}

// ---------------------------------------------------------------------------
// Xcur = leaky_relu(agg) + Xcur ;  res += Xcur_new * scale
// ---------------------------------------------------------------------------
__global__ void update_kernel(const float* __restrict__ agg,
                              float* __restrict__ Xcur,
                              float* __restrict__ res,
                              float scale, int nd) {
    int i = blockIdx.x * blockDim.x + threadIdx.x;
    if (i < nd) {
        float a   = agg[i];
        float act = a >= 0.f ? a : NEG_SLOPE * a;
        float xn  = act + Xcur[i];
        Xcur[i] = xn;
        res[i] += xn * scale;
    }
}

extern "C" void kernel_launch(void* const* d_in, const int* in_sizes, int n_in,
                              void* d_out, int out_size, void* d_ws, size_t ws_size,
                              hipStream_t stream) {
    const float* X   = (const float*)d_in[0];
    const int*   adj = (const int*)d_in[1];
    const float* W   = (const float*)d_in[2];
    const float* b   = (const float*)d_in[3];
    float* out = (float*)d_out;

    const int nd = in_sizes[0];          // N * 64
    const int n  = nd >> 6;              // N
    const int e  = in_sizes[1] / 2;      // E
    const int L  = in_sizes[3] / 64;     // layers

    const int* src = adj;
    const int* dst = adj + e;

    float* dinv = (float*)d_ws;                 // n floats (deg, then rsqrt'd)
    float* Xcur = dinv + n;                     // nd floats
    float* xw   = Xcur + (size_t)nd;            // nd floats
    float* agg  = xw   + (size_t)nd;            // nd floats

    const int B = 256;
    // 1. init
    init_kernel<<<(nd + B - 1) / B, B, 0, stream>>>(X, Xcur, out, dinv, n, nd);
    // 2. degrees
    degree_kernel<<<(e + B - 1) / B, B, 0, stream>>>(dst, dinv, e);
    // 3. dinv
    rsqrt_kernel<<<(n + B - 1) / B, B, 0, stream>>>(dinv, n);

    long long et = (long long)e * 64;
    int scatter_blocks = (int)((et + B - 1) / B);

    for (int i = 0; i < L; ++i) {
        const float* Wi = W + (size_t)i * 64 * 64;
        const float* bi = b + (size_t)i * 64;
        // a. dense transform
        gemm_kernel<<<(n + 3) / 4, B, 0, stream>>>(Xcur, Wi, xw, n);
        // b. agg = b + self-loop term
        agg_init_kernel<<<(nd + B - 1) / B, B, 0, stream>>>(xw, dinv, bi, agg, nd);
        // c. edge scatter
        scatter_kernel<<<scatter_blocks, B, 0, stream>>>(xw, src, dst, dinv, agg, e);
        // d. activation + residual + running sum
        update_kernel<<<(nd + B - 1) / B, B, 0, stream>>>(agg, Xcur, out,
                                                          1.0f / (float)(i + 2), nd);
    }
}

// Round 2
// 570.232 us; speedup vs baseline: 1.9264x; 1.9264x over previous
//
#include <hip/hip_runtime.h>

#define NEG_SLOPE 0.01f

// ---------------------------------------------------------------------------
// init: Xcur = X, res(d_out) = X, cnt = 0
// ---------------------------------------------------------------------------
__global__ void init_kernel(const float* __restrict__ X,
                            float* __restrict__ Xcur,
                            float* __restrict__ res,
                            int* __restrict__ cnt,
                            int n, int nd) {
    int i = blockIdx.x * blockDim.x + threadIdx.x;
    if (i < nd) {
        float v = X[i];
        Xcur[i] = v;
        res[i]  = v;
    }
    if (i < n) cnt[i] = 0;
}

// cnt[dst[e]] += 1 for each real edge
__global__ void degcnt_kernel(const int* __restrict__ dst,
                              int* __restrict__ cnt, int e) {
    int i = blockIdx.x * blockDim.x + threadIdx.x;
    if (i < e) atomicAdd(&cnt[dst[i]], 1);
}

// dinv[i] = rsqrt(cnt[i] + 1)   (+1 = self loop)
__global__ void dinv_kernel(const int* __restrict__ cnt,
                            float* __restrict__ dinv, int n) {
    int i = blockIdx.x * blockDim.x + threadIdx.x;
    if (i < n) dinv[i] = rsqrtf((float)cnt[i] + 1.0f);
}

// per-256-block sums of cnt
__global__ void blocksum_kernel(const int* __restrict__ cnt,
                                int* __restrict__ bsum, int n) {
    __shared__ int l[256];
    int i = blockIdx.x * 256 + threadIdx.x;
    l[threadIdx.x] = (i < n) ? cnt[i] : 0;
    __syncthreads();
    for (int s = 128; s > 0; s >>= 1) {
        if (threadIdx.x < s) l[threadIdx.x] += l[threadIdx.x + s];
        __syncthreads();
    }
    if (threadIdx.x == 0) bsum[blockIdx.x] = l[0];
}

// single-block exclusive scan of bsum (nb <= 1024)
__global__ __launch_bounds__(1024) void scanb_kernel(int* __restrict__ bsum, int nb) {
    __shared__ int l[1024];
    int t = threadIdx.x;
    l[t] = (t < nb) ? bsum[t] : 0;
    __syncthreads();
    for (int s = 1; s < 1024; s <<= 1) {
        int v = (t >= s) ? l[t - s] : 0;
        __syncthreads();
        l[t] += v;
        __syncthreads();
    }
    int ex = (t == 0) ? 0 : l[t - 1];
    if (t < nb) bsum[t] = ex;
}

// rowptr[i] = bsum[block] + exclusive_scan_within_block(cnt); rowptr[n] = E
__global__ void rowptr_kernel(const int* __restrict__ cnt,
                              const int* __restrict__ bsum,
                              int* __restrict__ rowptr, int n) {
    __shared__ int l[256];
    int t = threadIdx.x;
    int i = blockIdx.x * 256 + t;
    int c = (i < n) ? cnt[i] : 0;
    l[t] = c;
    __syncthreads();
    for (int s = 1; s < 256; s <<= 1) {
        int v = (t >= s) ? l[t - s] : 0;
        __syncthreads();
        l[t] += v;
        __syncthreads();
    }
    int incl = l[t];
    int base = bsum[blockIdx.x];
    if (i < n) {
        rowptr[i] = base + incl - c;
        if (i == n - 1) rowptr[n] = base + incl;
    }
}

// cursor = rowptr[0..n-1]
__global__ void cursor_kernel(const int* __restrict__ rowptr,
                              int* __restrict__ cursor, int n) {
    int i = blockIdx.x * blockDim.x + threadIdx.x;
    if (i < n) cursor[i] = rowptr[i];
}

// fill CSR: csr_src[slot]=src, csr_norm[slot]=dinv[src]*dinv[dst]
__global__ void fill_kernel(const int* __restrict__ src,
                            const int* __restrict__ dst,
                            const float* __restrict__ dinv,
                            int* __restrict__ cursor,
                            int* __restrict__ csr_src,
                            float* __restrict__ csr_norm, int e) {
    int i = blockIdx.x * blockDim.x + threadIdx.x;
    if (i < e) {
        int d = dst[i];
        int s = src[i];
        int slot = atomicAdd(&cursor[d], 1);
        csr_src[slot]  = s;
        csr_norm[slot] = dinv[s] * dinv[d];
    }
}

// ---------------------------------------------------------------------------
// xw = Xcur @ W   (64x64 W in LDS; 4 rows per 256-thread block)
// ---------------------------------------------------------------------------
__global__ __launch_bounds__(256) void gemm_kernel(const float* __restrict__ Xc,
                                                   const float* __restrict__ W,
                                                   float* __restrict__ xw, int n) {
    __shared__ float Wl[64 * 64];
    __shared__ float Xl[4 * 64];
    int tid = threadIdx.x;
    #pragma unroll
    for (int j = 0; j < 16; ++j) Wl[j * 256 + tid] = W[j * 256 + tid];

    int lr  = tid >> 6;
    int c   = tid & 63;
    int row = blockIdx.x * 4 + lr;
    if (row < n) Xl[lr * 64 + c] = Xc[row * 64 + c];
    __syncthreads();
    if (row < n) {
        float acc = 0.f;
        #pragma unroll
        for (int k = 0; k < 64; ++k)
            acc += Xl[lr * 64 + k] * Wl[k * 64 + c];
        xw[row * 64 + c] = acc;
    }
}

// ---------------------------------------------------------------------------
// fused pull aggregation + activation + residual + running sum
// one wave per node, lane = channel
// ---------------------------------------------------------------------------
__global__ __launch_bounds__(256) void agg_fused_kernel(const float* __restrict__ xw,
                                                        const int* __restrict__ rowptr,
                                                        const int* __restrict__ csr_src,
                                                        const float* __restrict__ csr_norm,
                                                        const float* __restrict__ dinv,
                                                        const float* __restrict__ b,
                                                        float* __restrict__ Xcur,
                                                        float* __restrict__ res,
                                                        float scale, int n) {
    int wid = (blockIdx.x * 256 + threadIdx.x) >> 6;  // node
    int c   = threadIdx.x & 63;                        // channel
    if (wid >= n) return;

    float dv  = dinv[wid];
    size_t vo = (size_t)wid * 64 + c;
    float acc = b[c] + xw[vo] * dv * dv;               // self-loop + bias

    int beg = rowptr[wid], end = rowptr[wid + 1];
    int k = beg;
    for (; k + 1 < end; k += 2) {
        int   s0 = csr_src[k],      s1 = csr_src[k + 1];
        float w0 = csr_norm[k],     w1 = csr_norm[k + 1];
        acc += xw[(size_t)s0 * 64 + c] * w0;
        acc += xw[(size_t)s1 * 64 + c] * w1;
    }
    if (k < end) {
        int   s0 = csr_src[k];
        float w0 = csr_norm[k];
        acc += xw[(size_t)s0 * 64 + c] * w0;
    }

    float act = acc >= 0.f ? acc : NEG_SLOPE * acc;
    float xn  = act + Xcur[vo];
    Xcur[vo] = xn;
    res[vo] += xn * scale;
}

extern "C" void kernel_launch(void* const* d_in, const int* in_sizes, int n_in,
                              void* d_out, int out_size, void* d_ws, size_t ws_size,
                              hipStream_t stream) {
    const float* X   = (const float*)d_in[0];
    const int*   adj = (const int*)d_in[1];
    const float* W   = (const float*)d_in[2];
    const float* b   = (const float*)d_in[3];
    float* out = (float*)d_out;

    const int nd = in_sizes[0];          // N * 64
    const int n  = nd >> 6;              // N
    const int e  = in_sizes[1] / 2;      // E
    const int L  = in_sizes[3] / 64;     // layers

    const int* src = adj;
    const int* dst = adj + e;

    const int B  = 256;
    const int nb = (n + B - 1) / B;

    // workspace layout (4-byte elements)
    int*   cnt      = (int*)d_ws;                      // n
    int*   bsum     = cnt + n;                         // nb
    int*   rowptr   = bsum + nb;                       // n+1
    int*   cursor   = rowptr + (n + 1);                // n
    float* dinv     = (float*)(cursor + n);            // n
    int*   csr_src  = (int*)(dinv + n);                // e
    float* csr_norm = (float*)(csr_src + e);           // e
    float* Xcur     = csr_norm + e;                    // nd
    float* xw       = Xcur + (size_t)nd;               // nd

    // ---- preprocessing: degrees, dinv, CSR build ----
    init_kernel<<<(nd + B - 1) / B, B, 0, stream>>>(X, Xcur, out, cnt, n, nd);
    degcnt_kernel<<<(e + B - 1) / B, B, 0, stream>>>(dst, cnt, e);
    dinv_kernel<<<nb, B, 0, stream>>>(cnt, dinv, n);
    blocksum_kernel<<<nb, B, 0, stream>>>(cnt, bsum, n);
    scanb_kernel<<<1, 1024, 0, stream>>>(bsum, nb);
    rowptr_kernel<<<nb, B, 0, stream>>>(cnt, bsum, rowptr, n);
    cursor_kernel<<<nb, B, 0, stream>>>(rowptr, cursor, n);
    fill_kernel<<<(e + B - 1) / B, B, 0, stream>>>(src, dst, dinv, cursor,
                                                   csr_src, csr_norm, e);

    // ---- layers ----
    int agg_blocks = (n * 64 + B - 1) / B;   // one wave per node
    for (int i = 0; i < L; ++i) {
        const float* Wi = W + (size_t)i * 64 * 64;
        const float* bi = b + (size_t)i * 64;
        gemm_kernel<<<(n + 3) / 4, B, 0, stream>>>(Xcur, Wi, xw, n);
        agg_fused_kernel<<<agg_blocks, B, 0, stream>>>(xw, rowptr, csr_src, csr_norm,
                                                       dinv, bi, Xcur, out,
                                                       1.0f / (float)(i + 2), n);
    }
}

// Round 3
// 522.019 us; speedup vs baseline: 2.1043x; 1.0924x over previous
//
#include <hip/hip_runtime.h>

#define NEG_SLOPE 0.01f

typedef unsigned short ushort_t;

static __device__ __forceinline__ float bf2f(ushort_t u) {
    return __uint_as_float(((unsigned int)u) << 16);
}
static __device__ __forceinline__ ushort_t f2bf(float f) {
    unsigned int x = __float_as_uint(f);
    x += 0x7fffu + ((x >> 16) & 1u);   // round-to-nearest-even
    return (ushort_t)(x >> 16);
}

// cnt[dst[e]] += 1 for each real edge
__global__ void degcnt_kernel(const int* __restrict__ dst,
                              int* __restrict__ cnt, int e) {
    int i = blockIdx.x * blockDim.x + threadIdx.x;
    if (i < e) atomicAdd(&cnt[dst[i]], 1);
}

// per-256-block sums of cnt
__global__ void blocksum_kernel(const int* __restrict__ cnt,
                                int* __restrict__ bsum, int n) {
    __shared__ int l[256];
    int i = blockIdx.x * 256 + threadIdx.x;
    l[threadIdx.x] = (i < n) ? cnt[i] : 0;
    __syncthreads();
    for (int s = 128; s > 0; s >>= 1) {
        if (threadIdx.x < s) l[threadIdx.x] += l[threadIdx.x + s];
        __syncthreads();
    }
    if (threadIdx.x == 0) bsum[blockIdx.x] = l[0];
}

// single-block exclusive scan of bsum (nb <= 1024)
__global__ __launch_bounds__(1024) void scanb_kernel(int* __restrict__ bsum, int nb) {
    __shared__ int l[1024];
    int t = threadIdx.x;
    l[t] = (t < nb) ? bsum[t] : 0;
    __syncthreads();
    for (int s = 1; s < 1024; s <<= 1) {
        int v = (t >= s) ? l[t - s] : 0;
        __syncthreads();
        l[t] += v;
        __syncthreads();
    }
    int ex = (t == 0) ? 0 : l[t - 1];
    if (t < nb) bsum[t] = ex;
}

// rowptr + cursor + dinv in one pass
__global__ void rowptr_kernel(const int* __restrict__ cnt,
                              const int* __restrict__ bsum,
                              int* __restrict__ rowptr,
                              int* __restrict__ cursor,
                              float* __restrict__ dinv, int n) {
    __shared__ int l[256];
    int t = threadIdx.x;
    int i = blockIdx.x * 256 + t;
    int cv = (i < n) ? cnt[i] : 0;
    l[t] = cv;
    __syncthreads();
    for (int s = 1; s < 256; s <<= 1) {
        int v = (t >= s) ? l[t - s] : 0;
        __syncthreads();
        l[t] += v;
        __syncthreads();
    }
    int incl = l[t];
    int base = bsum[blockIdx.x];
    if (i < n) {
        int rp = base + incl - cv;
        rowptr[i] = rp;
        cursor[i] = rp;
        dinv[i]   = rsqrtf((float)cv + 1.0f);
        if (i == n - 1) rowptr[n] = base + incl;
    }
}

// fill packed CSR: csr[slot] = (src, norm)
__global__ void fill_kernel(const int* __restrict__ src,
                            const int* __restrict__ dst,
                            const float* __restrict__ dinv,
                            int* __restrict__ cursor,
                            int2* __restrict__ csr, int e) {
    int i = blockIdx.x * blockDim.x + threadIdx.x;
    if (i < e) {
        int d = dst[i];
        int s = src[i];
        int slot = atomicAdd(&cursor[d], 1);
        csr[slot] = make_int2(s, __float_as_int(dinv[s] * dinv[d]));
    }
}

// xw = X @ W0  (f32 compute, bf16 store); 4 rows per 256-thread block
__global__ __launch_bounds__(256) void gemm_kernel(const float* __restrict__ Xc,
                                                   const float* __restrict__ W,
                                                   ushort_t* __restrict__ xw, int n) {
    __shared__ float Wl[64 * 64];
    __shared__ float Xl[4 * 64];
    int tid = threadIdx.x;
    #pragma unroll
    for (int j = 0; j < 16; ++j) Wl[j * 256 + tid] = W[j * 256 + tid];

    int lr  = tid >> 6;
    int c   = tid & 63;
    int row = blockIdx.x * 4 + lr;
    if (row < n) Xl[lr * 64 + c] = Xc[row * 64 + c];
    __syncthreads();
    if (row < n) {
        float acc = 0.f;
        #pragma unroll
        for (int k = 0; k < 64; ++k)
            acc += Xl[lr * 64 + k] * Wl[k * 64 + c];
        xw[row * 64 + c] = f2bf(acc);
    }
}

// ---------------------------------------------------------------------------
// fused: pull aggregation + leakyReLU + residual + running sum
//        + next-layer transform (xn @ Wn -> xwn, bf16)
// one wave per node, lane = channel
// ---------------------------------------------------------------------------
__global__ __launch_bounds__(256) void agg_fused_kernel(
        const ushort_t* __restrict__ xw,     // this layer's xw (bf16)
        const int*  __restrict__ rowptr,
        const int2* __restrict__ csr,
        const float* __restrict__ dinv,
        const float* __restrict__ b,         // this layer's bias
        const float* __restrict__ Wn,        // next layer W (nullptr if none)
        const float* __restrict__ xin,       // Xcur in (X for layer 0)
        float* __restrict__ xout,            // Xcur out
        const float* __restrict__ rin,       // res in (X for layer 0)
        float* __restrict__ rout,            // res out
        ushort_t* __restrict__ xwn,          // next xw out (bf16), if Wn
        float scale, int n) {
    __shared__ float Wl[64 * 64];
    int tid = threadIdx.x;
    const bool hasW = (Wn != nullptr);
    if (hasW) {
        #pragma unroll
        for (int j = 0; j < 16; ++j) Wl[j * 256 + tid] = Wn[j * 256 + tid];
        __syncthreads();
    }

    int wid = (blockIdx.x * 256 + tid) >> 6;   // node
    int c   = tid & 63;                        // channel
    if (wid >= n) return;

    float dv  = dinv[wid];
    size_t vo = (size_t)wid * 64 + c;
    float acc0 = b[c] + bf2f(xw[vo]) * dv * dv;   // bias + self-loop
    float acc1 = 0.f;

    int beg = rowptr[wid], end = rowptr[wid + 1];
    int k = beg;
    for (; k + 3 < end; k += 4) {
        int2 e0 = csr[k], e1 = csr[k + 1], e2 = csr[k + 2], e3 = csr[k + 3];
        acc0 += bf2f(xw[(size_t)e0.x * 64 + c]) * __int_as_float(e0.y);
        acc1 += bf2f(xw[(size_t)e1.x * 64 + c]) * __int_as_float(e1.y);
        acc0 += bf2f(xw[(size_t)e2.x * 64 + c]) * __int_as_float(e2.y);
        acc1 += bf2f(xw[(size_t)e3.x * 64 + c]) * __int_as_float(e3.y);
    }
    for (; k < end; ++k) {
        int2 e0 = csr[k];
        acc0 += bf2f(xw[(size_t)e0.x * 64 + c]) * __int_as_float(e0.y);
    }
    float acc = acc0 + acc1;

    float act = acc >= 0.f ? acc : NEG_SLOPE * acc;
    float xn  = act + xin[vo];
    xout[vo] = xn;
    rout[vo] = rin[vo] + xn * scale;

    if (hasW) {
        // xwn[wid][c] = sum_k xn_k * Wn[k][c]; xn_k via wave broadcast
        float o = 0.f;
        #pragma unroll
        for (int kk = 0; kk < 64; ++kk) {
            float xk = __shfl(xn, kk, 64);
            o += xk * Wl[kk * 64 + c];
        }
        xwn[vo] = f2bf(o);
    }
}

extern "C" void kernel_launch(void* const* d_in, const int* in_sizes, int n_in,
                              void* d_out, int out_size, void* d_ws, size_t ws_size,
                              hipStream_t stream) {
    const float* X   = (const float*)d_in[0];
    const int*   adj = (const int*)d_in[1];
    const float* W   = (const float*)d_in[2];
    const float* b   = (const float*)d_in[3];
    float* out = (float*)d_out;

    const int nd = in_sizes[0];          // N * 64
    const int n  = nd >> 6;              // N
    const int e  = in_sizes[1] / 2;      // E
    const int L  = in_sizes[3] / 64;     // layers

    const int* src = adj;
    const int* dst = adj + e;

    const int B  = 256;
    const int nb = (n + B - 1) / B;

    // workspace layout (csr first for 8B alignment)
    int2*  csr    = (int2*)d_ws;                        // e int2
    int*   cnt    = (int*)(csr + e);                    // n
    int*   bsum   = cnt + n;                            // nb
    int*   rowptr = bsum + nb;                          // n+1
    int*   cursor = rowptr + (n + 1);                   // n
    float* dinv   = (float*)(cursor + n);               // n
    float* Xcur   = dinv + n;                           // nd f32
    ushort_t* xwA = (ushort_t*)(Xcur + (size_t)nd);     // nd bf16
    ushort_t* xwB = xwA + (size_t)nd;                   // nd bf16

    // ---- preprocessing: degrees, CSR build ----
    hipMemsetAsync(cnt, 0, (size_t)n * sizeof(int), stream);
    degcnt_kernel<<<(e + B - 1) / B, B, 0, stream>>>(dst, cnt, e);
    blocksum_kernel<<<nb, B, 0, stream>>>(cnt, bsum, n);
    scanb_kernel<<<1, 1024, 0, stream>>>(bsum, nb);
    rowptr_kernel<<<nb, B, 0, stream>>>(cnt, bsum, rowptr, cursor, dinv, n);
    fill_kernel<<<(e + B - 1) / B, B, 0, stream>>>(src, dst, dinv, cursor, csr, e);

    // ---- layer 0 transform ----
    gemm_kernel<<<(n + 3) / 4, B, 0, stream>>>(X, W, xwA, n);

    // ---- layers (transform of layer i+1 fused into layer i's aggregation) ----
    int agg_blocks = (nd + B - 1) / B;   // one wave per node
    ushort_t* xw_in  = xwA;
    ushort_t* xw_out = xwB;
    for (int i = 0; i < L; ++i) {
        const bool last = (i == L - 1);
        const float* Wn = last ? nullptr : (W + (size_t)(i + 1) * 64 * 64);
        const float* bi = b + (size_t)i * 64;
        const float* xin = (i == 0) ? X : Xcur;
        const float* rin = (i == 0) ? X : out;
        agg_fused_kernel<<<agg_blocks, B, 0, stream>>>(
            xw_in, rowptr, csr, dinv, bi, Wn,
            xin, Xcur, rin, out,
            last ? nullptr : xw_out,
            1.0f / (float)(i + 2), n);
        ushort_t* t = xw_in; xw_in = xw_out; xw_out = t;
    }
}

// Round 4
// 424.865 us; speedup vs baseline: 2.5855x; 1.2287x over previous
//
#include <hip/hip_runtime.h>

#define NEG_SLOPE 0.01f
typedef unsigned short ushort_t;

static __device__ __forceinline__ float bf2f(ushort_t u) {
    return __uint_as_float(((unsigned int)u) << 16);
}
static __device__ __forceinline__ ushort_t f2bf(float f) {
    unsigned int x = __float_as_uint(f);
    x += 0x7fffu + ((x >> 16) & 1u);   // round-to-nearest-even
    return (ushort_t)(x >> 16);
}
static __device__ __forceinline__ float bcastf(float v, int lane) {
    return __int_as_float(__builtin_amdgcn_readlane(__float_as_int(v), lane));
}

// ---------------------------------------------------------------------------
// preprocessing (unchanged from round 3)
// ---------------------------------------------------------------------------
__global__ void degcnt_kernel(const int* __restrict__ dst,
                              int* __restrict__ cnt, int e) {
    int i = blockIdx.x * blockDim.x + threadIdx.x;
    if (i < e) atomicAdd(&cnt[dst[i]], 1);
}

__global__ void blocksum_kernel(const int* __restrict__ cnt,
                                int* __restrict__ bsum, int n) {
    __shared__ int l[256];
    int i = blockIdx.x * 256 + threadIdx.x;
    l[threadIdx.x] = (i < n) ? cnt[i] : 0;
    __syncthreads();
    for (int s = 128; s > 0; s >>= 1) {
        if (threadIdx.x < s) l[threadIdx.x] += l[threadIdx.x + s];
        __syncthreads();
    }
    if (threadIdx.x == 0) bsum[blockIdx.x] = l[0];
}

__global__ __launch_bounds__(1024) void scanb_kernel(int* __restrict__ bsum, int nb) {
    __shared__ int l[1024];
    int t = threadIdx.x;
    l[t] = (t < nb) ? bsum[t] : 0;
    __syncthreads();
    for (int s = 1; s < 1024; s <<= 1) {
        int v = (t >= s) ? l[t - s] : 0;
        __syncthreads();
        l[t] += v;
        __syncthreads();
    }
    int ex = (t == 0) ? 0 : l[t - 1];
    if (t < nb) bsum[t] = ex;
}

__global__ void rowptr_kernel(const int* __restrict__ cnt,
                              const int* __restrict__ bsum,
                              int* __restrict__ rowptr,
                              int* __restrict__ cursor,
                              float* __restrict__ dinv, int n) {
    __shared__ int l[256];
    int t = threadIdx.x;
    int i = blockIdx.x * 256 + t;
    int cv = (i < n) ? cnt[i] : 0;
    l[t] = cv;
    __syncthreads();
    for (int s = 1; s < 256; s <<= 1) {
        int v = (t >= s) ? l[t - s] : 0;
        __syncthreads();
        l[t] += v;
        __syncthreads();
    }
    int incl = l[t];
    int base = bsum[blockIdx.x];
    if (i < n) {
        int rp = base + incl - cv;
        rowptr[i] = rp;
        cursor[i] = rp;
        dinv[i]   = rsqrtf((float)cv + 1.0f);
        if (i == n - 1) rowptr[n] = base + incl;
    }
}

__global__ void fill_kernel(const int* __restrict__ src,
                            const int* __restrict__ dst,
                            const float* __restrict__ dinv,
                            int* __restrict__ cursor,
                            int2* __restrict__ csr, int e) {
    int i = blockIdx.x * blockDim.x + threadIdx.x;
    if (i < e) {
        int d = dst[i];
        int s = src[i];
        int slot = atomicAdd(&cursor[d], 1);
        csr[slot] = make_int2(s, __float_as_int(dinv[s] * dinv[d]));
    }
}

// ---------------------------------------------------------------------------
// xw = Xc @ W  (f32 in, bf16 out). W column c lives in lane-c VGPRs;
// X rows broadcast via v_readlane from a coalesced float4 load. No LDS.
// One wave = 16 rows (4 iterations x 4 rows).
// ---------------------------------------------------------------------------
__global__ __launch_bounds__(256) void gemm_rl(const float* __restrict__ Xc,
                                               const float* __restrict__ W,
                                               ushort_t* __restrict__ xw, int n) {
    int lane = threadIdx.x & 63;
    int wv   = threadIdx.x >> 6;

    float Wreg[64];
    #pragma unroll
    for (int k = 0; k < 64; ++k) Wreg[k] = W[k * 64 + lane];

    int row0 = blockIdx.x * 64 + wv * 16;
    int lr = lane >> 4;   // row-in-group this lane loads
    int lc = lane & 15;   // float4 slot

    #pragma unroll 1
    for (int it = 0; it < 4; ++it) {
        int r = row0 + it * 4;
        float4 xv = make_float4(0.f, 0.f, 0.f, 0.f);
        if (r + lr < n)
            xv = *(const float4*)(Xc + (size_t)(r + lr) * 64 + lc * 4);
        float xr[4] = {xv.x, xv.y, xv.z, xv.w};

        float a0 = 0.f, a1 = 0.f, a2 = 0.f, a3 = 0.f;
        #pragma unroll
        for (int k = 0; k < 64; ++k) {
            float w = Wreg[k];
            a0 = fmaf(bcastf(xr[k & 3],      (k >> 2)), w, a0);
            a1 = fmaf(bcastf(xr[k & 3], 16 + (k >> 2)), w, a1);
            a2 = fmaf(bcastf(xr[k & 3], 32 + (k >> 2)), w, a2);
            a3 = fmaf(bcastf(xr[k & 3], 48 + (k >> 2)), w, a3);
        }
        if (r + 0 < n) xw[(size_t)(r + 0) * 64 + lane] = f2bf(a0);
        if (r + 1 < n) xw[(size_t)(r + 1) * 64 + lane] = f2bf(a1);
        if (r + 2 < n) xw[(size_t)(r + 2) * 64 + lane] = f2bf(a2);
        if (r + 3 < n) xw[(size_t)(r + 3) * 64 + lane] = f2bf(a3);
    }
}

// ---------------------------------------------------------------------------
// pure pull aggregation + leakyReLU + residual + running sum.
// One wave per node, lane = channel. CSR segment loaded coalesced (lane j
// gets edge j), broadcast via v_readlane; 8 independent gathers in flight.
// ---------------------------------------------------------------------------
__global__ __launch_bounds__(256) void agg_kernel(
        const ushort_t* __restrict__ xw,
        const int*  __restrict__ rowptr,
        const int2* __restrict__ csr,
        const float* __restrict__ dinv,
        const float* __restrict__ b,
        const float* __restrict__ xin,
        float* __restrict__ xout,
        const float* __restrict__ rin,
        float* __restrict__ rout,
        float scale, int n) {
    int c   = threadIdx.x & 63;
    int wid = __builtin_amdgcn_readfirstlane(blockIdx.x * 4 + (threadIdx.x >> 6));
    if (wid >= n) return;

    float dv  = dinv[wid];
    size_t vo = (size_t)wid * 64 + c;
    float acc = b[c] + bf2f(xw[vo]) * (dv * dv);   // bias + self-loop

    int beg = rowptr[wid];
    int end = rowptr[wid + 1];

    for (int base = beg; base < end; base += 64) {
        int m = end - base;
        if (m > 64) m = 64;
        int2 ce = make_int2(0, 0);                 // s=0, w=0.0f for idle lanes
        if (c < m) ce = csr[base + c];             // coalesced segment load

        for (int j0 = 0; j0 < m; j0 += 8) {
            float g[8], wt[8];
            #pragma unroll
            for (int j = 0; j < 8; ++j) {
                int s  = __builtin_amdgcn_readlane(ce.x, j0 + j);
                int wb = __builtin_amdgcn_readlane(ce.y, j0 + j);
                wt[j]  = __int_as_float(wb);
                g[j]   = bf2f(xw[(size_t)(unsigned)s * 64 + c]);
            }
            #pragma unroll
            for (int j = 0; j < 8; ++j) acc = fmaf(g[j], wt[j], acc);
        }
    }

    float act = acc >= 0.f ? acc : NEG_SLOPE * acc;
    float xn  = act + xin[vo];
    xout[vo] = xn;
    rout[vo] = rin[vo] + xn * scale;
}

extern "C" void kernel_launch(void* const* d_in, const int* in_sizes, int n_in,
                              void* d_out, int out_size, void* d_ws, size_t ws_size,
                              hipStream_t stream) {
    const float* X   = (const float*)d_in[0];
    const int*   adj = (const int*)d_in[1];
    const float* W   = (const float*)d_in[2];
    const float* b   = (const float*)d_in[3];
    float* out = (float*)d_out;

    const int nd = in_sizes[0];          // N * 64
    const int n  = nd >> 6;              // N
    const int e  = in_sizes[1] / 2;      // E
    const int L  = in_sizes[3] / 64;     // layers

    const int* src = adj;
    const int* dst = adj + e;

    const int B  = 256;
    const int nb = (n + B - 1) / B;

    // workspace layout (csr first for 8B alignment)
    int2*  csr    = (int2*)d_ws;                        // e int2
    int*   cnt    = (int*)(csr + e);                    // n
    int*   bsum   = cnt + n;                            // nb
    int*   rowptr = bsum + nb;                          // n+1
    int*   cursor = rowptr + (n + 1);                   // n
    float* dinv   = (float*)(cursor + n);               // n
    float* Xcur   = dinv + n;                           // nd f32
    ushort_t* xwA = (ushort_t*)(Xcur + (size_t)nd);     // nd bf16

    // ---- preprocessing: degrees, CSR build ----
    hipMemsetAsync(cnt, 0, (size_t)n * sizeof(int), stream);
    degcnt_kernel<<<(e + B - 1) / B, B, 0, stream>>>(dst, cnt, e);
    blocksum_kernel<<<nb, B, 0, stream>>>(cnt, bsum, n);
    scanb_kernel<<<1, 1024, 0, stream>>>(bsum, nb);
    rowptr_kernel<<<nb, B, 0, stream>>>(cnt, bsum, rowptr, cursor, dinv, n);
    fill_kernel<<<(e + B - 1) / B, B, 0, stream>>>(src, dst, dinv, cursor, csr, e);

    // ---- layers ----
    int gemm_blocks = (n + 63) / 64;
    int agg_blocks  = (n + 3) / 4;
    for (int i = 0; i < L; ++i) {
        const float* Wi  = W + (size_t)i * 64 * 64;
        const float* bi  = b + (size_t)i * 64;
        const float* xin = (i == 0) ? X : Xcur;
        const float* rin = (i == 0) ? X : out;
        gemm_rl<<<gemm_blocks, B, 0, stream>>>(xin, Wi, xwA, n);
        agg_kernel<<<agg_blocks, B, 0, stream>>>(xwA, rowptr, csr, dinv, bi,
                                                 xin, Xcur, rin, out,
                                                 1.0f / (float)(i + 2), n);
    }
}

// Round 5
// 423.233 us; speedup vs baseline: 2.5955x; 1.0039x over previous
//
#include <hip/hip_runtime.h>

#define NEG_SLOPE 0.01f
typedef unsigned short ushort_t;

static __device__ __forceinline__ float bf2f(ushort_t u) {
    return __uint_as_float(((unsigned int)u) << 16);
}
static __device__ __forceinline__ ushort_t f2bf(float f) {
    unsigned int x = __float_as_uint(f);
    x += 0x7fffu + ((x >> 16) & 1u);   // round-to-nearest-even
    return (ushort_t)(x >> 16);
}
static __device__ __forceinline__ float bcastf(float v, int lane) {
    return __int_as_float(__builtin_amdgcn_readlane(__float_as_int(v), lane));
}

// ---------------------------------------------------------------------------
// degree count + CSR pre-init to sentinel n (grid-stride)
// ---------------------------------------------------------------------------
__global__ void degcnt_kernel(const int* __restrict__ dst,
                              int* __restrict__ cnt,
                              int* __restrict__ csr, int csr_len,
                              int e, int n) {
    int i = blockIdx.x * blockDim.x + threadIdx.x;
    if (i < e) atomicAdd(&cnt[dst[i]], 1);
    int stride = gridDim.x * blockDim.x;
    for (int j = i; j < csr_len; j += stride) csr[j] = n;
}

// per-256-block sums of PADDED counts
__global__ void blocksum_kernel(const int* __restrict__ cnt,
                                int* __restrict__ bsum, int n) {
    __shared__ int l[256];
    int i = blockIdx.x * 256 + threadIdx.x;
    l[threadIdx.x] = (i < n) ? ((cnt[i] + 7) & ~7) : 0;
    __syncthreads();
    for (int s = 128; s > 0; s >>= 1) {
        if (threadIdx.x < s) l[threadIdx.x] += l[threadIdx.x + s];
        __syncthreads();
    }
    if (threadIdx.x == 0) bsum[blockIdx.x] = l[0];
}

__global__ __launch_bounds__(1024) void scanb_kernel(int* __restrict__ bsum, int nb) {
    __shared__ int l[1024];
    int t = threadIdx.x;
    l[t] = (t < nb) ? bsum[t] : 0;
    __syncthreads();
    for (int s = 1; s < 1024; s <<= 1) {
        int v = (t >= s) ? l[t - s] : 0;
        __syncthreads();
        l[t] += v;
        __syncthreads();
    }
    int ex = (t == 0) ? 0 : l[t - 1];
    if (t < nb) bsum[t] = ex;
}

// rowptr (padded) + cursor + dinv + zero the sentinel xws rows
__global__ void rowptr_kernel(const int* __restrict__ cnt,
                              const int* __restrict__ bsum,
                              int* __restrict__ rowptr,
                              int* __restrict__ cursor,
                              float* __restrict__ dinv,
                              ushort_t* __restrict__ xwsA,
                              ushort_t* __restrict__ xwsB, int n) {
    __shared__ int l[256];
    int t = threadIdx.x;
    int i = blockIdx.x * 256 + t;
    int cvr = (i < n) ? cnt[i] : 0;        // real degree
    int cv  = (cvr + 7) & ~7;              // padded
    l[t] = cv;
    __syncthreads();
    for (int s = 1; s < 256; s <<= 1) {
        int v = (t >= s) ? l[t - s] : 0;
        __syncthreads();
        l[t] += v;
        __syncthreads();
    }
    int incl = l[t];
    int base = bsum[blockIdx.x];
    if (i < n) {
        int rp = base + incl - cv;
        rowptr[i] = rp;
        cursor[i] = rp;
        dinv[i]   = rsqrtf((float)cvr + 1.0f);
        if (i == n - 1) rowptr[n] = base + incl;
    }
    if (blockIdx.x == 0 && t < 64) {       // zero sentinel row n
        xwsA[(size_t)n * 64 + t] = 0;
        xwsB[(size_t)n * 64 + t] = 0;
    }
}

// fill CSR: 4-byte payload (src only); padding slots keep sentinel n
__global__ void fill_kernel(const int* __restrict__ src,
                            const int* __restrict__ dst,
                            int* __restrict__ cursor,
                            int* __restrict__ csr, int e) {
    int i = blockIdx.x * blockDim.x + threadIdx.x;
    if (i < e) {
        int slot = atomicAdd(&cursor[dst[i]], 1);
        csr[slot] = src[i];
    }
}

// ---------------------------------------------------------------------------
// xws = (Xc @ W) * dinv[row]  (f32 in, bf16 out). W column in lane VGPRs,
// X rows broadcast via readlane. One wave = 16 rows.
// ---------------------------------------------------------------------------
__global__ __launch_bounds__(256) void gemm_rl(const float* __restrict__ Xc,
                                               const float* __restrict__ W,
                                               const float* __restrict__ dinv,
                                               ushort_t* __restrict__ xws, int n) {
    int lane = threadIdx.x & 63;
    int wv   = threadIdx.x >> 6;

    float Wreg[64];
    #pragma unroll
    for (int k = 0; k < 64; ++k) Wreg[k] = W[k * 64 + lane];

    int row0 = blockIdx.x * 64 + wv * 16;
    int lr = lane >> 4;
    int lc = lane & 15;

    #pragma unroll 1
    for (int it = 0; it < 4; ++it) {
        int r = row0 + it * 4;
        float4 xv = make_float4(0.f, 0.f, 0.f, 0.f);
        if (r + lr < n)
            xv = *(const float4*)(Xc + (size_t)(r + lr) * 64 + lc * 4);
        float xr[4] = {xv.x, xv.y, xv.z, xv.w};

        float a0 = 0.f, a1 = 0.f, a2 = 0.f, a3 = 0.f;
        #pragma unroll
        for (int k = 0; k < 64; ++k) {
            float w = Wreg[k];
            a0 = fmaf(bcastf(xr[k & 3],      (k >> 2)), w, a0);
            a1 = fmaf(bcastf(xr[k & 3], 16 + (k >> 2)), w, a1);
            a2 = fmaf(bcastf(xr[k & 3], 32 + (k >> 2)), w, a2);
            a3 = fmaf(bcastf(xr[k & 3], 48 + (k >> 2)), w, a3);
        }
        if (r + 0 < n) xws[(size_t)(r + 0) * 64 + lane] = f2bf(a0 * dinv[r + 0]);
        if (r + 1 < n) xws[(size_t)(r + 1) * 64 + lane] = f2bf(a1 * dinv[r + 1]);
        if (r + 2 < n) xws[(size_t)(r + 2) * 64 + lane] = f2bf(a2 * dinv[r + 2]);
        if (r + 3 < n) xws[(size_t)(r + 3) * 64 + lane] = f2bf(a3 * dinv[r + 3]);
    }
}

// ---------------------------------------------------------------------------
// fused: pull aggregation (pre-scaled xws, weight-free) + leakyReLU +
// residual + running sum [+ next-layer transform via W-in-VGPR readlane].
// One wave per node, lane = channel. Segments padded to 8 with sentinel n.
// ---------------------------------------------------------------------------
template<int HASW>
__global__ __launch_bounds__(256) void agg_kernel(
        const ushort_t* __restrict__ xws,
        const int* __restrict__ rowptr,
        const int* __restrict__ csr,
        const float* __restrict__ dinv,
        const float* __restrict__ b,
        const float* __restrict__ Wn,
        const float* __restrict__ xin,
        float* __restrict__ xout,
        const float* __restrict__ rin,
        float* __restrict__ rout,
        ushort_t* __restrict__ xws_next,
        float scale, int n) {
    int tid = threadIdx.x;
    int c   = tid & 63;
    int wid = blockIdx.x * 4 + (tid >> 6);

    float Wreg[HASW ? 64 : 1];
    if (HASW) {
        #pragma unroll
        for (int k = 0; k < 64; ++k) Wreg[k] = Wn[k * 64 + c];
    }
    if (wid >= n) return;

    float dv  = dinv[wid];
    size_t vo = (size_t)wid * 64 + c;
    float acc = bf2f(xws[vo]);               // self term (already * dv)

    int beg = rowptr[wid];
    int end = rowptr[wid + 1];
    for (int base = beg; base < end; base += 64) {
        int m = end - base; if (m > 64) m = 64;   // multiple of 8
        int ce = csr[base + c];                   // coalesced segment load
        int j0 = 0;
        for (; j0 + 16 <= m; j0 += 16) {
            float g[16];
            #pragma unroll
            for (int j = 0; j < 16; ++j) {
                int s = __builtin_amdgcn_readlane(ce, j0 + j);
                g[j] = bf2f(xws[(size_t)(unsigned)s * 64 + c]);
            }
            #pragma unroll
            for (int j = 0; j < 16; ++j) acc += g[j];
        }
        if (j0 < m) {                             // exactly 8 left
            float g[8];
            #pragma unroll
            for (int j = 0; j < 8; ++j) {
                int s = __builtin_amdgcn_readlane(ce, j0 + j);
                g[j] = bf2f(xws[(size_t)(unsigned)s * 64 + c]);
            }
            #pragma unroll
            for (int j = 0; j < 8; ++j) acc += g[j];
        }
    }

    float r0  = b[c] + dv * acc;
    float act = r0 >= 0.f ? r0 : NEG_SLOPE * r0;
    float xn  = act + xin[vo];
    xout[vo] = xn;
    rout[vo] = rin[vo] + xn * scale;

    if (HASW) {
        float o = 0.f;
        #pragma unroll
        for (int k = 0; k < 64; ++k)
            o = fmaf(bcastf(xn, k), Wreg[k], o);
        xws_next[vo] = f2bf(o * dv);              // pre-scale for next layer
    }
}

extern "C" void kernel_launch(void* const* d_in, const int* in_sizes, int n_in,
                              void* d_out, int out_size, void* d_ws, size_t ws_size,
                              hipStream_t stream) {
    const float* X   = (const float*)d_in[0];
    const int*   adj = (const int*)d_in[1];
    const float* W   = (const float*)d_in[2];
    const float* b   = (const float*)d_in[3];
    float* out = (float*)d_out;

    const int nd = in_sizes[0];          // N * 64
    const int n  = nd >> 6;              // N
    const int e  = in_sizes[1] / 2;      // E
    const int L  = in_sizes[3] / 64;     // layers (3)

    const int* src = adj;
    const int* dst = adj + e;

    const int B  = 256;
    const int nb = (n + B - 1) / B;
    const int csr_len = e + 8 * n + 64;  // padded segments + slack

    // workspace layout
    int*   csr    = (int*)d_ws;                         // csr_len
    int*   cnt    = csr + csr_len;                      // n
    int*   bsum   = cnt + n;                            // nb
    int*   rowptr = bsum + nb;                          // n+1
    int*   cursor = rowptr + (n + 1);                   // n
    float* dinv   = (float*)(cursor + n);               // n
    float* Xcur   = dinv + n;                           // nd f32
    ushort_t* xwsA = (ushort_t*)(Xcur + (size_t)nd);    // nd + 64 bf16
    ushort_t* xwsB = xwsA + (size_t)nd + 64;            // nd + 64 bf16

    // ---- preprocessing ----
    hipMemsetAsync(cnt, 0, (size_t)n * sizeof(int), stream);
    degcnt_kernel<<<(e + B - 1) / B, B, 0, stream>>>(dst, cnt, csr, csr_len, e, n);
    blocksum_kernel<<<nb, B, 0, stream>>>(cnt, bsum, n);
    scanb_kernel<<<1, 1024, 0, stream>>>(bsum, nb);
    rowptr_kernel<<<nb, B, 0, stream>>>(cnt, bsum, rowptr, cursor, dinv,
                                        xwsA, xwsB, n);
    fill_kernel<<<(e + B - 1) / B, B, 0, stream>>>(src, dst, cursor, csr, e);

    // ---- layer 0 transform ----
    gemm_rl<<<(n + 63) / 64, B, 0, stream>>>(X, W, dinv, xwsA, n);

    // ---- layers; next-layer transform fused into aggregation ----
    int agg_blocks = (n + 3) / 4;
    // layer 0
    agg_kernel<1><<<agg_blocks, B, 0, stream>>>(
        xwsA, rowptr, csr, dinv, b, W + 64 * 64,
        X, Xcur, X, out, xwsB, 1.0f / 2.0f, n);
    // layer 1
    agg_kernel<1><<<agg_blocks, B, 0, stream>>>(
        xwsB, rowptr, csr, dinv, b + 64, W + 2 * 64 * 64,
        Xcur, Xcur, out, out, xwsA, 1.0f / 3.0f, n);
    // layer 2 (no next transform)
    agg_kernel<0><<<agg_blocks, B, 0, stream>>>(
        xwsA, rowptr, csr, dinv, b + 128, nullptr,
        Xcur, Xcur, out, out, nullptr, 1.0f / 4.0f, n);
}